// Round 10
// baseline (199.395 us; speedup 1.0000x reference)
//
#include <hip/hip_runtime.h>

typedef unsigned short u16;
typedef __attribute__((ext_vector_type(8))) short short8;   // 8 bf16 = 4 VGPRs
typedef __attribute__((ext_vector_type(4))) float f32x4;
typedef __attribute__((ext_vector_type(4))) unsigned short u16x4;

#define NSEQ 8
#define LD 2048
#define LM 512
#define DD 1024
#define HID 1024
#define M1 (NSEQ*LD)   // 16384 input rows
#define M2 (NSEQ*LM)   // 4096 memory rows

// async global->LDS, 16B per lane; LDS dest is wave-uniform base + lane*16
#define GLOAD_LDS16(gp, lp) __builtin_amdgcn_global_load_lds( \
    (const __attribute__((address_space(1))) unsigned int*)(gp), \
    (__attribute__((address_space(3))) unsigned int*)(lp), 16, 0, 0)

__device__ __forceinline__ u16 f2bf(float f) {
    union { float f; unsigned int i; } v; v.f = f;
    unsigned int r = v.i + 0x7fffu + ((v.i >> 16) & 1u);
    return (u16)(r >> 16);
}
__device__ __forceinline__ float bf2f(u16 u) {
    union { unsigned int i; float f; } v; v.i = ((unsigned int)u) << 16; return v.f;
}

// ---- prep: rows -> bf16 + dots; tail blocks do the weight transposes ----
__global__ __launch_bounds__(256) void prep_all(
    const float* __restrict__ input, const float* __restrict__ memory,
    const float* __restrict__ in1_w, const float* __restrict__ mem1_w,
    const float* __restrict__ mask,
    const float* __restrict__ in2_w, const float* __restrict__ mem2_w,
    u16* __restrict__ input_bf16, u16* __restrict__ memory_bf16,
    u16* __restrict__ in2_wt, u16* __restrict__ mem2_wt,
    float* __restrict__ idot, float* __restrict__ mdotm) {
    __shared__ float tile[32][33];
    const int b = blockIdx.x, t = threadIdx.x;
    if (b < M1 + M2) {
        const float* src; const float* w; u16* dst;
        if (b < M1) { src = input + (size_t)b * DD; w = in1_w;
                      dst = input_bf16 + (size_t)b * DD; }
        else { const int rm = b - M1; src = memory + (size_t)rm * DD; w = mem1_w;
               dst = memory_bf16 + (size_t)rm * DD; }
        f32x4 v = *(const f32x4*)(src + t * 4);
        f32x4 wv = *(const f32x4*)(w + t * 4);
        u16x4 o;
        #pragma unroll
        for (int i = 0; i < 4; i++) o[i] = f2bf(v[i]);
        *(u16x4*)(dst + t * 4) = o;
        float s = v[0]*wv[0] + v[1]*wv[1] + v[2]*wv[2] + v[3]*wv[3];
        #pragma unroll
        for (int off = 32; off; off >>= 1) s += __shfl_down(s, off);
        if ((t & 63) == 0) tile[0][t >> 6] = s;
        __syncthreads();
        if (t == 0) {
            const float d = tile[0][0] + tile[0][1] + tile[0][2] + tile[0][3];
            if (b < M1) idot[b] = d;
            else { const int rm = b - M1;
                   mdotm[rm] = d - 1e30f * (1.0f - mask[rm]); }
        }
    } else {
        const int wb = b - (M1 + M2);          // 0..2047
        const int z = wb >> 10;
        const int tid = wb & 1023;
        const int c0 = (tid & 31) * 32, r0 = (tid >> 5) * 32;
        const float* src = z ? mem2_w : in2_w;
        u16* dst = z ? mem2_wt : in2_wt;
        const int tx = t & 31, ty = t >> 5;
        #pragma unroll
        for (int yy = ty; yy < 32; yy += 8)
            tile[yy][tx] = src[(size_t)(r0 + yy) * DD + c0 + tx];
        __syncthreads();
        #pragma unroll
        for (int yy = ty; yy < 32; yy += 8)
            dst[(size_t)(c0 + yy) * DD + r0 + tx] = f2bf(tile[tx][yy]);
    }
}

// ==== merged kernel: blocks 0..255 = att GEMM+softmax, 256..511 = mem2 ===
__global__ __launch_bounds__(512, 1) void mm_att(
    const u16* __restrict__ A, const u16* __restrict__ B,
    const float* __restrict__ idot, const float* __restrict__ mdotm,
    u16* __restrict__ P, float* __restrict__ rowmax,
    const u16* __restrict__ Wm, float* __restrict__ out0,
    const float* __restrict__ bias, u16* __restrict__ mem2t) {
    __shared__ __align__(16) u16 lds[61440];   // 120 KB (max of both paths)
    const int t = threadIdx.x, lane = t & 63, wave = t >> 6;
    const int wm = wave >> 2, wn = wave & 3;
    const int lr = lane & 15, kg = lane >> 4;
    const int srow = lane >> 3;

    if (blockIdx.x < 256) {
        // ================= att path (verbatim round-9 structure) =========
        constexpr int ABUF = 64 * 64;
        constexpr int BBUF = 256 * 64;
        constexpr int BUFE = ABUF + BBUF;      // 20480 u16 = 40 KB
        const int bid = blockIdx.x;
        const int swz = (bid & 7) * 32 + (bid >> 3);   // XCD swizzle
        const int m0 = swz * 64;
        const int nb = m0 >> 11;
        const u16* Bp = B + (size_t)nb * LM * DD;

        const u16* gA;
        {
            const int colb = ((lane & 7) * 16) ^ ((((wave << 2) + (lane >> 4)) & 7) << 4);
            gA = A + (size_t)(m0 + wave * 8 + srow) * DD + (colb >> 1);
        }
        const u16* gB[4];
        #pragma unroll
        for (int i = 0; i < 4; i++) {
            const int c = wave * 4 + i;
            const int colb = ((lane & 7) * 16) ^ ((((c << 2) + (lane >> 4)) & 7) << 4);
            gB[i] = Bp + (size_t)(c * 8 + srow) * DD + (colb >> 1);
        }
        int offA[2], offB[4];
        #pragma unroll
        for (int i = 0; i < 2; i++) {
            const int row = wm * 32 + i * 16 + lr;
            offA[i] = (row * 128 + kg * 16) ^ (((row >> 1) & 7) << 4);
        }
        #pragma unroll
        for (int j = 0; j < 4; j++) {
            const int row = wn * 64 + j * 16 + lr;
            offB[j] = (ABUF * 2 + row * 128 + kg * 16) ^ (((row >> 1) & 7) << 4);
        }

        f32x4 acc[2][8];
        #pragma unroll
        for (int i = 0; i < 2; i++)
            #pragma unroll
            for (int j = 0; j < 8; j++) acc[i][j] = (f32x4){0.f, 0.f, 0.f, 0.f};

        #define ASTAGE(tt, buf, pofs) do {                                  \
            u16* la_ = &lds[(buf) * BUFE];                                  \
            u16* lb_ = la_ + ABUF;                                          \
            const int ko_ = (tt) * 64;                                      \
            GLOAD_LDS16(gA + ko_, la_ + wave * 512);                        \
            _Pragma("unroll")                                               \
            for (int i_ = 0; i_ < 4; i_++)                                  \
                GLOAD_LDS16(gB[i_] + (pofs) + ko_, lb_ + (wave * 4 + i_) * 512); \
        } while (0)

        for (int c = 0; c < 2; c++) {
            const size_t pofs = (size_t)c * 256 * DD;
            ASTAGE(0, 0, pofs);
            ASTAGE(1, 1, pofs);
            asm volatile("s_waitcnt vmcnt(5)" ::: "memory");
            __builtin_amdgcn_s_barrier();
            __builtin_amdgcn_sched_barrier(0);
            int cb = 0, sb = 2;
            for (int tt = 0; tt < 16; ++tt) {
                if (tt + 2 < 16) ASTAGE(tt + 2, sb, pofs);
                __builtin_amdgcn_sched_barrier(0);
                const char* bb = (const char*)&lds[cb * BUFE];
                short8 af[2][2];
                #pragma unroll
                for (int i = 0; i < 2; i++)
                    #pragma unroll
                    for (int kh = 0; kh < 2; kh++)
                        af[i][kh] = *(const short8*)(bb + (offA[i] ^ (kh * 64)));
                #pragma unroll
                for (int j = 0; j < 4; j++) {
                    short8 bf[2];
                    #pragma unroll
                    for (int kh = 0; kh < 2; kh++)
                        bf[kh] = *(const short8*)(bb + (offB[j] ^ (kh * 64)));
                    __builtin_amdgcn_s_setprio(1);
                    #pragma unroll
                    for (int i = 0; i < 2; i++)
                        #pragma unroll
                        for (int kh = 0; kh < 2; kh++)
                            acc[i][c * 4 + j] = __builtin_amdgcn_mfma_f32_16x16x32_bf16(
                                af[i][kh], bf[kh], acc[i][c * 4 + j], 0, 0, 0);
                    __builtin_amdgcn_s_setprio(0);
                }
                if (tt + 2 < 16)      asm volatile("s_waitcnt vmcnt(5)" ::: "memory");
                else if (tt + 1 < 16) asm volatile("s_waitcnt vmcnt(0)" ::: "memory");
                __builtin_amdgcn_s_barrier();
                __builtin_amdgcn_sched_barrier(0);
                cb = (cb == 2) ? 0 : cb + 1;
                sb = (sb == 2) ? 0 : sb + 1;
            }
        }
        #undef ASTAGE

        // epilogue: dots + row softmax + write P
        float* redm = (float*)lds;
        float* reds = redm + 256;
        float mdv[8];
        #pragma unroll
        for (int cj = 0; cj < 8; cj++)
            mdv[cj] = mdotm[nb * LM + (cj >> 2) * 256 + wn * 64 + (cj & 3) * 16 + lr];
        float idv[8];
        #pragma unroll
        for (int i = 0; i < 2; i++)
            #pragma unroll
            for (int r = 0; r < 4; r++)
                idv[i * 4 + r] = idot[m0 + wm * 32 + i * 16 + kg * 4 + r];
        float pm[8];
        #pragma unroll
        for (int i = 0; i < 2; i++)
            #pragma unroll
            for (int r = 0; r < 4; r++) {
                float mx = -3.0e38f;
                #pragma unroll
                for (int cj = 0; cj < 8; cj++) {
                    const float v = acc[i][cj][r] * 0.03125f + idv[i * 4 + r] + mdv[cj];
                    acc[i][cj][r] = v;
                    mx = fmaxf(mx, v);
                }
                pm[i * 4 + r] = mx;
            }
        #pragma unroll
        for (int w = 1; w < 16; w <<= 1)
            #pragma unroll
            for (int q = 0; q < 8; q++) pm[q] = fmaxf(pm[q], __shfl_xor(pm[q], w));
        if (lr == 0) {
            #pragma unroll
            for (int i = 0; i < 2; i++)
                #pragma unroll
                for (int r = 0; r < 4; r++)
                    redm[(wm * 32 + i * 16 + kg * 4 + r) * 4 + wn] = pm[i * 4 + r];
        }
        __syncthreads();
        float Mr[8], ps[8];
        #pragma unroll
        for (int i = 0; i < 2; i++)
            #pragma unroll
            for (int r = 0; r < 4; r++) {
                const int row = wm * 32 + i * 16 + kg * 4 + r;
                const float a = fmaxf(redm[row * 4 + 0], redm[row * 4 + 1]);
                const float b2 = fmaxf(redm[row * 4 + 2], redm[row * 4 + 3]);
                Mr[i * 4 + r] = fmaxf(a, b2);
                float s = 0.f;
                #pragma unroll
                for (int cj = 0; cj < 8; cj++) {
                    const float e = __expf(acc[i][cj][r] - Mr[i * 4 + r]);
                    acc[i][cj][r] = e;
                    s += e;
                }
                ps[i * 4 + r] = s;
            }
        #pragma unroll
        for (int w = 1; w < 16; w <<= 1)
            #pragma unroll
            for (int q = 0; q < 8; q++) ps[q] += __shfl_xor(ps[q], w);
        if (lr == 0) {
            #pragma unroll
            for (int i = 0; i < 2; i++)
                #pragma unroll
                for (int r = 0; r < 4; r++)
                    reds[(wm * 32 + i * 16 + kg * 4 + r) * 4 + wn] = ps[i * 4 + r];
        }
        __syncthreads();
        #pragma unroll
        for (int i = 0; i < 2; i++)
            #pragma unroll
            for (int r = 0; r < 4; r++) {
                const int row = wm * 32 + i * 16 + kg * 4 + r;
                const float inv = 1.0f / (reds[row * 4 + 0] + reds[row * 4 + 1] +
                                          reds[row * 4 + 2] + reds[row * 4 + 3]);
                if (wn == 0 && lr == 0) rowmax[m0 + row] = Mr[i * 4 + r];
                #pragma unroll
                for (int cj = 0; cj < 8; cj++)
                    P[(size_t)(m0 + row) * LM +
                      (cj >> 2) * 256 + wn * 64 + (cj & 3) * 16 + lr] =
                        f2bf(acc[i][cj][r] * inv);
            }
    } else {
        // ================= mem2 path (verbatim gemm_mem2, NT=16) =========
        constexpr int AI = 2, BM = 128;
        constexpr int BUFE = (BM + 128) * 64;
        const int bid = blockIdx.x - 256;
        const int swz = (bid & 7) * 32 + (bid >> 3);
        const int m0 = (swz >> 3) * BM, n0 = (swz & 7) * 128;

        const u16* gA[AI];
        const u16* gB[2];
        #pragma unroll
        for (int i = 0; i < AI; i++) {
            const int c = wave * AI + i;
            const int colb = ((lane & 7) * 16) ^ ((((c << 2) + (lane >> 4)) & 7) << 4);
            gA[i] = B /*memory_bf16*/ + (size_t)(m0 + c * 8 + srow) * DD + (colb >> 1);
        }
        #pragma unroll
        for (int i = 0; i < 2; i++) {
            const int c = wave * 2 + i;
            const int colb = ((lane & 7) * 16) ^ ((((c << 2) + (lane >> 4)) & 7) << 4);
            gB[i] = Wm + (size_t)(n0 + c * 8 + srow) * DD + (colb >> 1);
        }
        int offA[2 * AI], offB[2];
        #pragma unroll
        for (int i = 0; i < 2 * AI; i++) {
            const int row = wm * (BM / 2) + i * 16 + lr;
            offA[i] = (row * 128 + kg * 16) ^ (((row >> 1) & 7) << 4);
        }
        #pragma unroll
        for (int j = 0; j < 2; j++) {
            const int row = wn * 32 + j * 16 + lr;
            offB[j] = (BM * 64 * 2 + row * 128 + kg * 16) ^ (((row >> 1) & 7) << 4);
        }

        f32x4 acc[2 * AI][2];
        #pragma unroll
        for (int i = 0; i < 2 * AI; i++)
            #pragma unroll
            for (int j = 0; j < 2; j++) acc[i][j] = (f32x4){0.f, 0.f, 0.f, 0.f};

        #define MSTAGE(tt, buf) do {                                        \
            u16* la_ = &lds[(buf) * BUFE];                                  \
            u16* lb_ = la_ + BM * 64;                                       \
            const int ko_ = (tt) * 64;                                      \
            _Pragma("unroll")                                               \
            for (int i_ = 0; i_ < AI; i_++)                                 \
                GLOAD_LDS16(gA[i_] + ko_, la_ + (wave * AI + i_) * 512);    \
            _Pragma("unroll")                                               \
            for (int i_ = 0; i_ < 2; i_++)                                  \
                GLOAD_LDS16(gB[i_] + ko_, lb_ + (wave * 2 + i_) * 512);     \
        } while (0)

        MSTAGE(0, 0);
        MSTAGE(1, 1);
        asm volatile("s_waitcnt vmcnt(4)" ::: "memory");
        __builtin_amdgcn_s_barrier();
        __builtin_amdgcn_sched_barrier(0);

        int cb = 0, sb = 2;
        for (int tt = 0; tt < 16; ++tt) {
            if (tt + 2 < 16) MSTAGE(tt + 2, sb);
            __builtin_amdgcn_sched_barrier(0);
            const char* bb = (const char*)&lds[cb * BUFE];
            short8 bfr[2][2];
            #pragma unroll
            for (int j = 0; j < 2; j++)
                #pragma unroll
                for (int kh = 0; kh < 2; kh++)
                    bfr[j][kh] = *(const short8*)(bb + (offB[j] ^ (kh * 64)));
            #pragma unroll
            for (int p = 0; p < AI; p++) {
                short8 af[2][2];
                #pragma unroll
                for (int q = 0; q < 2; q++)
                    #pragma unroll
                    for (int kh = 0; kh < 2; kh++)
                        af[q][kh] = *(const short8*)(bb + (offA[2 * p + q] ^ (kh * 64)));
                __builtin_amdgcn_s_setprio(1);
                #pragma unroll
                for (int q = 0; q < 2; q++)
                    #pragma unroll
                    for (int j = 0; j < 2; j++)
                        #pragma unroll
                        for (int kh = 0; kh < 2; kh++)
                            acc[2 * p + q][j] = __builtin_amdgcn_mfma_f32_16x16x32_bf16(
                                af[q][kh], bfr[j][kh], acc[2 * p + q][j], 0, 0, 0);
                __builtin_amdgcn_s_setprio(0);
            }
            if (tt + 2 < 16)      asm volatile("s_waitcnt vmcnt(4)" ::: "memory");
            else if (tt + 1 < 16) asm volatile("s_waitcnt vmcnt(0)" ::: "memory");
            __builtin_amdgcn_s_barrier();
            __builtin_amdgcn_sched_barrier(0);
            cb = (cb == 2) ? 0 : cb + 1;
            sb = (sb == 2) ? 0 : sb + 1;
        }
        #undef MSTAGE

        // epilogue: f32 out (+bias) coalesced + bf16 transposed via LDS
        u16* ldsT = (u16*)lds;                       // [128 cols][136 rows]
        #pragma unroll
        for (int i = 0; i < 2 * AI; i++) {
            #pragma unroll
            for (int j = 0; j < 2; j++) {
                const int lcol = wn * 32 + j * 16 + lr;
                const float bv = bias[n0 + lcol];
                #pragma unroll
                for (int r = 0; r < 4; r++) {
                    const int lrow = wm * (BM / 2) + i * 16 + kg * 4 + r;
                    const float v = acc[i][j][r] + bv;
                    out0[(size_t)(m0 + lrow) * HID + n0 + lcol] = v;
                    ldsT[lcol * 136 + lrow] = f2bf(v);
                }
            }
        }
        __syncthreads();
        const int nb = m0 >> 9, mloc = m0 & 511;
        #pragma unroll
        for (int s = 0; s < 4; s++) {
            const int idx = s * 512 + t;
            const int hrow = idx >> 4, seg = idx & 15;
            short8 v8 = *(const short8*)&ldsT[hrow * 136 + seg * 8];
            *(short8*)&mem2t[((size_t)nb * HID + n0 + hrow) * LM + mloc + seg * 8] = v8;
        }
    }
}

// ==== fused inp2 + PV GEMM, BM=128 (proven AI=2 schedule), out 0..3 ======
__global__ __launch_bounds__(512, 1) void fused_gemm(
    const u16* __restrict__ A1, const u16* __restrict__ B1,
    const u16* __restrict__ A2, const u16* __restrict__ B2,
    float* __restrict__ out0,
    const float* __restrict__ bias, const float* __restrict__ ot) {
    constexpr int AI = 2, BM = 128;
    constexpr int BUFE = (BM + 128) * 64;          // 16384 u16
    __shared__ __align__(16) u16 lds[3 * BUFE];    // 96 KiB
    const int t = threadIdx.x;
    const int lane = t & 63, wave = t >> 6;
    const int wm = wave >> 2, wn = wave & 3;
    const int lr = lane & 15, kg = lane >> 4;
    const int bid = blockIdx.y * 8 + blockIdx.x;
    const int swz = (bid & 7) * gridDim.y + (bid >> 3);
    const int m0 = (swz >> 3) * BM, n0 = (swz & 7) * 128;
    const int nb = m0 / LD;
    const u16* B2p = B2 + (size_t)nb * HID * LM;

    const int srow = lane >> 3;
    int colbA[AI], colbB[2];
    const u16* gA[AI];
    const u16* gB[2];
    #pragma unroll
    for (int i = 0; i < AI; i++) {
        const int c = wave * AI + i;
        colbA[i] = ((lane & 7) * 16) ^ ((((c << 2) + (lane >> 4)) & 7) << 4);
        gA[i] = A1 + (size_t)(m0 + c * 8 + srow) * DD + (colbA[i] >> 1);
    }
    #pragma unroll
    for (int i = 0; i < 2; i++) {
        const int c = wave * 2 + i;
        colbB[i] = ((lane & 7) * 16) ^ ((((c << 2) + (lane >> 4)) & 7) << 4);
        gB[i] = B1 + (size_t)(n0 + c * 8 + srow) * DD + (colbB[i] >> 1);
    }
    int offA[2 * AI], offB[2];
    #pragma unroll
    for (int i = 0; i < 2 * AI; i++) {
        const int row = wm * (BM / 2) + i * 16 + lr;
        offA[i] = (row * 128 + kg * 16) ^ (((row >> 1) & 7) << 4);
    }
    #pragma unroll
    for (int j = 0; j < 2; j++) {
        const int row = wn * 32 + j * 16 + lr;
        offB[j] = (BM * 64 * 2 + row * 128 + kg * 16) ^ (((row >> 1) & 7) << 4);
    }

    #define STAGE(tt, buf) do {                                             \
        u16* la_ = &lds[(buf) * BUFE];                                      \
        u16* lb_ = la_ + BM * 64;                                           \
        const int ko_ = (tt) * 64;                                          \
        _Pragma("unroll")                                                   \
        for (int i_ = 0; i_ < AI; i_++)                                     \
            GLOAD_LDS16(gA[i_] + ko_, la_ + (wave * AI + i_) * 512);        \
        _Pragma("unroll")                                                   \
        for (int i_ = 0; i_ < 2; i_++)                                      \
            GLOAD_LDS16(gB[i_] + ko_, lb_ + (wave * 2 + i_) * 512);         \
    } while (0)

    #define KLOOP(NT, ACC)                                                  \
    do {                                                                    \
        STAGE(0, 0);                                                        \
        STAGE(1, 1);                                                        \
        asm volatile("s_waitcnt vmcnt(4)" ::: "memory");                    \
        __builtin_amdgcn_s_barrier();                                       \
        __builtin_amdgcn_sched_barrier(0);                                  \
        int cb = 0, sb = 2;                                                 \
        for (int tt = 0; tt < (NT); ++tt) {                                 \
            if (tt + 2 < (NT)) STAGE(tt + 2, sb);                           \
            __builtin_amdgcn_sched_barrier(0);                              \
            const char* bb = (const char*)&lds[cb * BUFE];                  \
            short8 bfr[2][2];                                               \
            _Pragma("unroll")                                               \
            for (int j = 0; j < 2; j++)                                     \
                _Pragma("unroll")                                           \
                for (int kh = 0; kh < 2; kh++)                              \
                    bfr[j][kh] = *(const short8*)(bb + (offB[j] ^ (kh * 64))); \
            _Pragma("unroll")                                               \
            for (int p = 0; p < AI; p++) {                                  \
                short8 af[2][2];                                            \
                _Pragma("unroll")                                           \
                for (int q = 0; q < 2; q++)                                 \
                    _Pragma("unroll")                                       \
                    for (int kh = 0; kh < 2; kh++)                          \
                        af[q][kh] = *(const short8*)(bb + (offA[2 * p + q] ^ (kh * 64))); \
                __builtin_amdgcn_s_setprio(1);                              \
                _Pragma("unroll")                                           \
                for (int q = 0; q < 2; q++)                                 \
                    _Pragma("unroll")                                       \
                    for (int j = 0; j < 2; j++)                             \
                        _Pragma("unroll")                                   \
                        for (int kh = 0; kh < 2; kh++)                      \
                            ACC[2 * p + q][j] = __builtin_amdgcn_mfma_f32_16x16x32_bf16( \
                                af[q][kh], bfr[j][kh], ACC[2 * p + q][j], 0, 0, 0); \
                __builtin_amdgcn_s_setprio(0);                              \
            }                                                               \
            if (tt + 2 < (NT))      asm volatile("s_waitcnt vmcnt(4)" ::: "memory"); \
            else if (tt + 1 < (NT)) asm volatile("s_waitcnt vmcnt(0)" ::: "memory"); \
            __builtin_amdgcn_s_barrier();                                   \
            __builtin_amdgcn_sched_barrier(0);                              \
            cb = (cb == 2) ? 0 : cb + 1;                                    \
            sb = (sb == 2) ? 0 : sb + 1;                                    \
        }                                                                   \
    } while (0)

    f32x4 acc1[2 * AI][2], acc2[2 * AI][2];
    #pragma unroll
    for (int i = 0; i < 2 * AI; i++)
        #pragma unroll
        for (int j = 0; j < 2; j++) {
            acc1[i][j] = (f32x4){0.f, 0.f, 0.f, 0.f};
            acc2[i][j] = (f32x4){0.f, 0.f, 0.f, 0.f};
        }

    KLOOP(16, acc1);   // inp2: K = 1024

    #pragma unroll
    for (int i = 0; i < AI; i++) {
        const int c = wave * AI + i;
        gA[i] = A2 + (size_t)(m0 + c * 8 + srow) * LM + (colbA[i] >> 1);
    }
    #pragma unroll
    for (int i = 0; i < 2; i++) {
        const int c = wave * 2 + i;
        gB[i] = B2p + (size_t)(n0 + c * 8 + srow) * LM + (colbB[i] >> 1);
    }

    KLOOP(8, acc2);    // PV: K = 512

    #undef KLOOP
    #undef STAGE

    #pragma unroll
    for (int i = 0; i < 2 * AI; i++) {
        #pragma unroll
        for (int j = 0; j < 2; j++) {
            const int col = n0 + wn * 32 + j * 16 + lr;
            const float b = bias[col];
            const float otv = ot[nb * HID + col];
            #pragma unroll
            for (int r = 0; r < 4; r++) {
                const int row = m0 + wm * (BM / 2) + i * 16 + kg * 4 + r;
                const size_t o = (size_t)row * 4096 + col;
                const float i2 = acc1[i][j][r] + b;
                const float o1 = acc2[i][j][r];
                out0[o] = i2;
                out0[o + 1024] = o1;
                out0[o + 2048] = i2 * o1;
                out0[o + 3072] = otv * o1;
            }
        }
    }
}

// ---- output_two via xbar = sum_l w2[l] * x_l (bf16 input, 256 blocks) ---
__global__ __launch_bounds__(256) void xbar_partial(
    const float* __restrict__ rowmax, const u16* __restrict__ X,
    float* __restrict__ part) {
    const int lz = blockIdx.x, n = blockIdx.y, t = threadIdx.x;   // lz 0..31
    const float* rm = rowmax + (size_t)n * LD;
    float v[8];
    float m = -3.0e38f;
    #pragma unroll
    for (int i = 0; i < 8; i++) { v[i] = rm[t + i * 256]; m = fmaxf(m, v[i]); }
    #pragma unroll
    for (int off = 32; off; off >>= 1) m = fmaxf(m, __shfl_down(m, off));
    __shared__ float sm[4], ss[4];
    __shared__ float wl[64];
    if ((t & 63) == 0) sm[t >> 6] = m;
    __syncthreads();
    const float M = fmaxf(fmaxf(sm[0], sm[1]), fmaxf(sm[2], sm[3]));
    float s = 0.f;
    #pragma unroll
    for (int i = 0; i < 8; i++) s += __expf(v[i] - M);
    #pragma unroll
    for (int off = 32; off; off >>= 1) s += __shfl_down(s, off);
    if ((t & 63) == 0) ss[t >> 6] = s;
    __syncthreads();
    const float invS = 1.0f / (ss[0] + ss[1] + ss[2] + ss[3]);
    if (t < 64) wl[t] = __expf(rm[lz * 64 + t] - M) * invS;
    __syncthreads();
    const u16* xp = X + ((size_t)n * LD + lz * 64) * DD + t * 4;
    f32x4 acc = {0.f, 0.f, 0.f, 0.f};
    #pragma unroll 4
    for (int l = 0; l < 64; l++) {
        u16x4 x = *(const u16x4*)(xp + (size_t)l * DD);
        const float w = wl[l];
        acc[0] += w * bf2f(x[0]); acc[1] += w * bf2f(x[1]);
        acc[2] += w * bf2f(x[2]); acc[3] += w * bf2f(x[3]);
    }
    *(f32x4*)&part[((size_t)n * 32 + lz) * HID + t * 4] = acc;
}

// ot[n][h] = xbar[n]·Wt[h,:] + b[h]; 64 blocks (8 h-chunks x 8 n)
__global__ __launch_bounds__(256) void ot_final2(
    const float* __restrict__ part, const u16* __restrict__ Wt,
    const float* __restrict__ bias, float* __restrict__ ot) {
    const int hc = blockIdx.x, n = blockIdx.y, t = threadIdx.x;
    __shared__ float xb[HID];
    f32x4 s = {0.f, 0.f, 0.f, 0.f};
    #pragma unroll
    for (int i = 0; i < 32; i++) {
        f32x4 p = *(const f32x4*)&part[((size_t)n * 32 + i) * HID + t * 4];
        s[0] += p[0]; s[1] += p[1]; s[2] += p[2]; s[3] += p[3];
    }
    *(f32x4*)&xb[t * 4] = s;
    __syncthreads();
    const int h = hc * 128 + (t >> 1);
    const int d0 = (t & 1) * 512;
    float a = 0.f;
    #pragma unroll 4
    for (int d = 0; d < 512; d += 8) {
        short8 w8 = *(const short8*)&Wt[(size_t)h * DD + d0 + d];
        #pragma unroll
        for (int j = 0; j < 8; j++) a += bf2f((u16)w8[j]) * xb[d0 + d + j];
    }
    a += __shfl_xor(a, 1);
    if ((t & 1) == 0) ot[(size_t)n * HID + h] = a + bias[h];
}

extern "C" void kernel_launch(void* const* d_in, const int* in_sizes, int n_in,
                              void* d_out, int out_size, void* d_ws, size_t ws_size,
                              hipStream_t stream) {
    const float* input  = (const float*)d_in[0];
    const float* memory = (const float*)d_in[1];
    const float* mask   = (const float*)d_in[2];
    const float* in1_w  = (const float*)d_in[3];
    const float* mem1_w = (const float*)d_in[4];
    const float* in2_w  = (const float*)d_in[5];
    const float* in2_b  = (const float*)d_in[6];
    const float* mem2_w = (const float*)d_in[7];
    const float* mem2_b = (const float*)d_in[8];

    float* out = (float*)d_out;
    float* outTail = out + (size_t)M1 * 4096;  // mem2 output [N,LM,HID]

    char* ws = (char*)d_ws;
    size_t off = 0;
    auto alloc = [&](size_t bytes) -> void* {
        void* p = ws + off;
        off = (off + bytes + 255) & ~(size_t)255;
        return p;
    };
    u16* input_bf16  = (u16*)alloc((size_t)M1 * DD * 2);      // 33.5 MB
    u16* memory_bf16 = (u16*)alloc((size_t)M2 * DD * 2);      // 8.4 MB
    u16* in2_wt      = (u16*)alloc((size_t)HID * DD * 2);     // 2.1 MB
    u16* mem2_wt     = (u16*)alloc((size_t)HID * DD * 2);     // 2.1 MB
    u16* mem2t       = (u16*)alloc((size_t)NSEQ * HID * LM * 2);  // 8.4 MB
    u16* P           = (u16*)alloc((size_t)M1 * LM * 2);      // 16.8 MB
    float* idot      = (float*)alloc((size_t)M1 * 4);
    float* mdotm     = (float*)alloc((size_t)M2 * 4);
    float* rowmax    = (float*)alloc((size_t)M1 * 4);
    float* ot        = (float*)alloc((size_t)NSEQ * HID * 4);
    float* part      = (float*)alloc((size_t)NSEQ * 32 * HID * 4);

    // 1) bf16 casts + row dots + weight transposes (merged)
    prep_all<<<M1 + M2 + 2048, 256, 0, stream>>>(
        input, memory, in1_w, mem1_w, mask, in2_w, mem2_w,
        input_bf16, memory_bf16, in2_wt, mem2_wt, idot, mdotm);
    // 2) merged: att GEMM+softmax (blocks 0..255) + mem2 GEMM (256..511)
    mm_att<<<512, 512, 0, stream>>>(
        input_bf16, memory_bf16, idot, mdotm, P, rowmax,
        mem2_wt, outTail, mem2_b, mem2t);
    // 3) output_two = (sum_l w2 x_l) @ W2 + b
    xbar_partial<<<dim3(32, NSEQ), 256, 0, stream>>>(rowmax, input_bf16, part);
    ot_final2<<<dim3(8, NSEQ), 256, 0, stream>>>(part, in2_wt, in2_b, ot);
    // 4) fused inp2 + PV (BM=128, 1024 blocks) -> out blocks 0..3
    fused_gemm<<<dim3(8, M1 / 128), 512, 0, stream>>>(
        input_bf16, in2_wt, P, mem2t, out, in2_b, ot);
}

// Round 11
// 195.687 us; speedup vs baseline: 1.0190x; 1.0190x over previous
//
#include <hip/hip_runtime.h>

typedef unsigned short u16;
typedef __attribute__((ext_vector_type(8))) short short8;   // 8 bf16 = 4 VGPRs
typedef __attribute__((ext_vector_type(4))) float f32x4;
typedef __attribute__((ext_vector_type(4))) unsigned short u16x4;

#define NSEQ 8
#define LD 2048
#define LM 512
#define DD 1024
#define HID 1024
#define M1 (NSEQ*LD)   // 16384 input rows
#define M2 (NSEQ*LM)   // 4096 memory rows

// async global->LDS, 16B per lane; LDS dest is wave-uniform base + lane*16
#define GLOAD_LDS16(gp, lp) __builtin_amdgcn_global_load_lds( \
    (const __attribute__((address_space(1))) unsigned int*)(gp), \
    (__attribute__((address_space(3))) unsigned int*)(lp), 16, 0, 0)

__device__ __forceinline__ u16 f2bf(float f) {
    union { float f; unsigned int i; } v; v.f = f;
    unsigned int r = v.i + 0x7fffu + ((v.i >> 16) & 1u);
    return (u16)(r >> 16);
}
__device__ __forceinline__ float bf2f(u16 u) {
    union { unsigned int i; float f; } v; v.i = ((unsigned int)u) << 16; return v.f;
}

// ---- prep: rows -> bf16 + dots; tail blocks do the weight transposes ----
__global__ __launch_bounds__(256) void prep_all(
    const float* __restrict__ input, const float* __restrict__ memory,
    const float* __restrict__ in1_w, const float* __restrict__ mem1_w,
    const float* __restrict__ mask,
    const float* __restrict__ in2_w, const float* __restrict__ mem2_w,
    u16* __restrict__ input_bf16, u16* __restrict__ memory_bf16,
    u16* __restrict__ in2_wt, u16* __restrict__ mem2_wt,
    float* __restrict__ idot, float* __restrict__ mdotm) {
    __shared__ float tile[32][33];
    const int b = blockIdx.x, t = threadIdx.x;
    if (b < M1 + M2) {
        const float* src; const float* w; u16* dst;
        if (b < M1) { src = input + (size_t)b * DD; w = in1_w;
                      dst = input_bf16 + (size_t)b * DD; }
        else { const int rm = b - M1; src = memory + (size_t)rm * DD; w = mem1_w;
               dst = memory_bf16 + (size_t)rm * DD; }
        f32x4 v = *(const f32x4*)(src + t * 4);
        f32x4 wv = *(const f32x4*)(w + t * 4);
        u16x4 o;
        #pragma unroll
        for (int i = 0; i < 4; i++) o[i] = f2bf(v[i]);
        *(u16x4*)(dst + t * 4) = o;
        float s = v[0]*wv[0] + v[1]*wv[1] + v[2]*wv[2] + v[3]*wv[3];
        #pragma unroll
        for (int off = 32; off; off >>= 1) s += __shfl_down(s, off);
        if ((t & 63) == 0) tile[0][t >> 6] = s;
        __syncthreads();
        if (t == 0) {
            const float d = tile[0][0] + tile[0][1] + tile[0][2] + tile[0][3];
            if (b < M1) idot[b] = d;
            else { const int rm = b - M1;
                   mdotm[rm] = d - 1e30f * (1.0f - mask[rm]); }
        }
    } else {
        const int wb = b - (M1 + M2);          // 0..2047
        const int z = wb >> 10;
        const int tid = wb & 1023;
        const int c0 = (tid & 31) * 32, r0 = (tid >> 5) * 32;
        const float* src = z ? mem2_w : in2_w;
        u16* dst = z ? mem2_wt : in2_wt;
        const int tx = t & 31, ty = t >> 5;
        #pragma unroll
        for (int yy = ty; yy < 32; yy += 8)
            tile[yy][tx] = src[(size_t)(r0 + yy) * DD + c0 + tx];
        __syncthreads();
        #pragma unroll
        for (int yy = ty; yy < 32; yy += 8)
            dst[(size_t)(c0 + yy) * DD + r0 + tx] = f2bf(tile[tx][yy]);
    }
}

// ==== 128x128 MFMA GEMM (3-buffer, counted vmcnt) for mem2 ===============
// writes f32 out (+bias) AND bf16 transposed mem2t via LDS transpose.
template <int NT>
__global__ __launch_bounds__(512, 1) void gemm_mem2(
    const u16* __restrict__ A, const u16* __restrict__ B,
    float* __restrict__ out0, const float* __restrict__ bias,
    u16* __restrict__ mem2t) {
    constexpr int AI = 2, BM = 128;
    constexpr int BUFE = (BM + 128) * 64;
    __shared__ __align__(16) u16 lds[3 * BUFE];    // 96 KiB
    const int t = threadIdx.x;
    const int lane = t & 63, wave = t >> 6;
    const int wm = wave >> 2, wn = wave & 3;
    const int lr = lane & 15, kg = lane >> 4;
    const int bid = blockIdx.y * 8 + blockIdx.x;
    const int swz = (bid & 7) * gridDim.y + (bid >> 3);
    const int m0 = (swz >> 3) * BM, n0 = (swz & 7) * 128;

    const int srow = lane >> 3;
    const u16* gA[AI];
    const u16* gB[2];
    #pragma unroll
    for (int i = 0; i < AI; i++) {
        const int c = wave * AI + i;
        const int colb = ((lane & 7) * 16) ^ ((((c << 2) + (lane >> 4)) & 7) << 4);
        gA[i] = A + (size_t)(m0 + c * 8 + srow) * DD + (colb >> 1);
    }
    #pragma unroll
    for (int i = 0; i < 2; i++) {
        const int c = wave * 2 + i;
        const int colb = ((lane & 7) * 16) ^ ((((c << 2) + (lane >> 4)) & 7) << 4);
        gB[i] = B + (size_t)(n0 + c * 8 + srow) * DD + (colb >> 1);
    }
    int offA[2 * AI], offB[2];
    #pragma unroll
    for (int i = 0; i < 2 * AI; i++) {
        const int row = wm * (BM / 2) + i * 16 + lr;
        offA[i] = (row * 128 + kg * 16) ^ (((row >> 1) & 7) << 4);
    }
    #pragma unroll
    for (int j = 0; j < 2; j++) {
        const int row = wn * 32 + j * 16 + lr;
        offB[j] = (BM * 64 * 2 + row * 128 + kg * 16) ^ (((row >> 1) & 7) << 4);
    }

    f32x4 acc[2 * AI][2];
    #pragma unroll
    for (int i = 0; i < 2 * AI; i++)
        #pragma unroll
        for (int j = 0; j < 2; j++) acc[i][j] = (f32x4){0.f, 0.f, 0.f, 0.f};

    #define STAGE(tt, buf) do {                                             \
        u16* la_ = &lds[(buf) * BUFE];                                      \
        u16* lb_ = la_ + BM * 64;                                           \
        const int ko_ = (tt) * 64;                                          \
        _Pragma("unroll")                                                   \
        for (int i_ = 0; i_ < AI; i_++)                                     \
            GLOAD_LDS16(gA[i_] + ko_, la_ + (wave * AI + i_) * 512);        \
        _Pragma("unroll")                                                   \
        for (int i_ = 0; i_ < 2; i_++)                                      \
            GLOAD_LDS16(gB[i_] + ko_, lb_ + (wave * 2 + i_) * 512);         \
    } while (0)

    STAGE(0, 0);
    STAGE(1, 1);
    asm volatile("s_waitcnt vmcnt(4)" ::: "memory");
    __builtin_amdgcn_s_barrier();
    __builtin_amdgcn_sched_barrier(0);

    int cb = 0, sb = 2;
    for (int tt = 0; tt < NT; ++tt) {
        if (tt + 2 < NT) STAGE(tt + 2, sb);
        __builtin_amdgcn_sched_barrier(0);
        const char* bb = (const char*)&lds[cb * BUFE];
        short8 bfr[2][2];
        #pragma unroll
        for (int j = 0; j < 2; j++)
            #pragma unroll
            for (int kh = 0; kh < 2; kh++)
                bfr[j][kh] = *(const short8*)(bb + (offB[j] ^ (kh * 64)));
        #pragma unroll
        for (int p = 0; p < AI; p++) {
            short8 af[2][2];
            #pragma unroll
            for (int q = 0; q < 2; q++)
                #pragma unroll
                for (int kh = 0; kh < 2; kh++)
                    af[q][kh] = *(const short8*)(bb + (offA[2 * p + q] ^ (kh * 64)));
            __builtin_amdgcn_s_setprio(1);
            #pragma unroll
            for (int q = 0; q < 2; q++)
                #pragma unroll
                for (int j = 0; j < 2; j++)
                    #pragma unroll
                    for (int kh = 0; kh < 2; kh++)
                        acc[2 * p + q][j] = __builtin_amdgcn_mfma_f32_16x16x32_bf16(
                            af[q][kh], bfr[j][kh], acc[2 * p + q][j], 0, 0, 0);
            __builtin_amdgcn_s_setprio(0);
        }
        if (tt + 2 < NT)      asm volatile("s_waitcnt vmcnt(4)" ::: "memory");
        else if (tt + 1 < NT) asm volatile("s_waitcnt vmcnt(0)" ::: "memory");
        __builtin_amdgcn_s_barrier();
        __builtin_amdgcn_sched_barrier(0);
        cb = (cb == 2) ? 0 : cb + 1;
        sb = (sb == 2) ? 0 : sb + 1;
    }
    #undef STAGE

    // epilogue: f32 out (coalesced) + bf16 into LDS transposed
    u16* ldsT = (u16*)lds;                       // [128 cols][136 rows]
    #pragma unroll
    for (int i = 0; i < 2 * AI; i++) {
        #pragma unroll
        for (int j = 0; j < 2; j++) {
            const int lcol = wn * 32 + j * 16 + lr;
            const float bv = bias[n0 + lcol];
            #pragma unroll
            for (int r = 0; r < 4; r++) {
                const int lrow = wm * (BM / 2) + i * 16 + kg * 4 + r;
                const float v = acc[i][j][r] + bv;
                out0[(size_t)(m0 + lrow) * HID + n0 + lcol] = v;
                ldsT[lcol * 136 + lrow] = f2bf(v);
            }
        }
    }
    __syncthreads();
    // coalesced bf16 write: mem2t[n][h][m]
    const int nb = m0 >> 9, mloc = m0 & 511;
    #pragma unroll
    for (int s = 0; s < 4; s++) {
        const int idx = s * 512 + t;
        const int hrow = idx >> 4, seg = idx & 15;
        short8 v8 = *(const short8*)&ldsT[hrow * 136 + seg * 8];
        *(short8*)&mem2t[((size_t)nb * HID + n0 + hrow) * LM + mloc + seg * 8] = v8;
    }
}

// ==== fused inp2-GEMM + PV-GEMM: writes out blocks 0..3 ==================
// epilogue via LDS-transpose: 64 fully-coalesced f32x4 stores per thread
// instead of 256 scattered dword stores.
__global__ __launch_bounds__(512, 2) void fused_gemm(
    const u16* __restrict__ A1, const u16* __restrict__ B1,
    const u16* __restrict__ A2, const u16* __restrict__ B2,
    float* __restrict__ out0,
    const float* __restrict__ bias, const float* __restrict__ ot) {
    constexpr int BUFE = (256 + 128) * 64;
    __shared__ __align__(16) u16 lds[3 * BUFE];       // 144 KiB
    const int t = threadIdx.x;
    const int lane = t & 63, wave = t >> 6;
    const int wm = wave >> 2, wn = wave & 3;
    const int lr = lane & 15, kg = lane >> 4;
    const int bid = blockIdx.y * 8 + blockIdx.x;
    const int swz = (bid & 7) * gridDim.y + (bid >> 3);
    const int m0 = (swz >> 3) * 256, n0 = (swz & 7) * 128;
    const int nb = m0 / LD;
    const u16* B2p = B2 + (size_t)nb * HID * LM;

    const int srow = lane >> 3;
    int colbA[4], colbB[2];
    const u16* gA[4];
    const u16* gB[2];
    #pragma unroll
    for (int i = 0; i < 4; i++) {
        const int c = wave * 4 + i;
        colbA[i] = ((lane & 7) * 16) ^ ((((c << 2) + (lane >> 4)) & 7) << 4);
        gA[i] = A1 + (size_t)(m0 + c * 8 + srow) * DD + (colbA[i] >> 1);
    }
    #pragma unroll
    for (int i = 0; i < 2; i++) {
        const int c = wave * 2 + i;
        colbB[i] = ((lane & 7) * 16) ^ ((((c << 2) + (lane >> 4)) & 7) << 4);
        gB[i] = B1 + (size_t)(n0 + c * 8 + srow) * DD + (colbB[i] >> 1);
    }
    int offA[8], offB[2];
    #pragma unroll
    for (int i = 0; i < 8; i++) {
        const int row = wm * 128 + i * 16 + lr;
        offA[i] = (row * 128 + kg * 16) ^ (((row >> 1) & 7) << 4);
    }
    #pragma unroll
    for (int j = 0; j < 2; j++) {
        const int row = wn * 32 + j * 16 + lr;
        offB[j] = (256 * 64 * 2 + row * 128 + kg * 16) ^ (((row >> 1) & 7) << 4);
    }

    #define STAGE(tt, buf) do {                                             \
        u16* la_ = &lds[(buf) * BUFE];                                      \
        u16* lb_ = la_ + 256 * 64;                                          \
        const int ko_ = (tt) * 64;                                          \
        _Pragma("unroll")                                                   \
        for (int i_ = 0; i_ < 4; i_++)                                      \
            GLOAD_LDS16(gA[i_] + ko_, la_ + (wave * 4 + i_) * 512);         \
        _Pragma("unroll")                                                   \
        for (int i_ = 0; i_ < 2; i_++)                                      \
            GLOAD_LDS16(gB[i_] + ko_, lb_ + (wave * 2 + i_) * 512);         \
    } while (0)

    #define KLOOP(NT, ACC)                                                  \
    do {                                                                    \
        STAGE(0, 0);                                                        \
        STAGE(1, 1);                                                        \
        asm volatile("s_waitcnt vmcnt(6)" ::: "memory");                    \
        __builtin_amdgcn_s_barrier();                                       \
        __builtin_amdgcn_sched_barrier(0);                                  \
        int cb = 0, sb = 2;                                                 \
        for (int tt = 0; tt < (NT); ++tt) {                                 \
            if (tt + 2 < (NT)) STAGE(tt + 2, sb);                           \
            __builtin_amdgcn_sched_barrier(0);                              \
            const char* bb = (const char*)&lds[cb * BUFE];                  \
            short8 bfr[2][2];                                               \
            _Pragma("unroll")                                               \
            for (int j = 0; j < 2; j++)                                     \
                _Pragma("unroll")                                           \
                for (int kh = 0; kh < 2; kh++)                              \
                    bfr[j][kh] = *(const short8*)(bb + (offB[j] ^ (kh * 64))); \
            _Pragma("unroll")                                               \
            for (int p = 0; p < 4; p++) {                                   \
                short8 af[2][2];                                            \
                _Pragma("unroll")                                           \
                for (int q = 0; q < 2; q++)                                 \
                    _Pragma("unroll")                                       \
                    for (int kh = 0; kh < 2; kh++)                          \
                        af[q][kh] = *(const short8*)(bb + (offA[2 * p + q] ^ (kh * 64))); \
                __builtin_amdgcn_s_setprio(1);                              \
                _Pragma("unroll")                                           \
                for (int q = 0; q < 2; q++)                                 \
                    _Pragma("unroll")                                       \
                    for (int j = 0; j < 2; j++)                             \
                        _Pragma("unroll")                                   \
                        for (int kh = 0; kh < 2; kh++)                      \
                            ACC[2 * p + q][j] = __builtin_amdgcn_mfma_f32_16x16x32_bf16( \
                                af[q][kh], bfr[j][kh], ACC[2 * p + q][j], 0, 0, 0); \
                __builtin_amdgcn_s_setprio(0);                              \
            }                                                               \
            if (tt + 2 < (NT))      asm volatile("s_waitcnt vmcnt(6)" ::: "memory"); \
            else if (tt + 1 < (NT)) asm volatile("s_waitcnt vmcnt(0)" ::: "memory"); \
            __builtin_amdgcn_s_barrier();                                   \
            __builtin_amdgcn_sched_barrier(0);                              \
            cb = (cb == 2) ? 0 : cb + 1;                                    \
            sb = (sb == 2) ? 0 : sb + 1;                                    \
        }                                                                   \
    } while (0)

    f32x4 acc1[8][2], acc2[8][2];
    #pragma unroll
    for (int i = 0; i < 8; i++)
        #pragma unroll
        for (int j = 0; j < 2; j++) {
            acc1[i][j] = (f32x4){0.f, 0.f, 0.f, 0.f};
            acc2[i][j] = (f32x4){0.f, 0.f, 0.f, 0.f};
        }

    KLOOP(16, acc1);   // inp2: K = 1024

    #pragma unroll
    for (int i = 0; i < 4; i++) {
        const int c = wave * 4 + i;
        gA[i] = A2 + (size_t)(m0 + c * 8 + srow) * LM + (colbA[i] >> 1);
    }
    #pragma unroll
    for (int i = 0; i < 2; i++) {
        const int c = wave * 2 + i;
        gB[i] = B2p + (size_t)(n0 + c * 8 + srow) * LM + (colbB[i] >> 1);
    }

    KLOOP(8, acc2);    // PV: K = 512

    #undef KLOOP
    #undef STAGE

    // ---- epilogue: i2 = acc1 + bias in place; otv per (j) ---------------
    float otv[2];
    #pragma unroll
    for (int j = 0; j < 2; j++) {
        const int colL = wn * 32 + j * 16 + lr;
        otv[j] = ot[nb * HID + n0 + colL];
        const float b = bias[n0 + colL];
        #pragma unroll
        for (int i = 0; i < 8; i++)
            #pragma unroll
            for (int r = 0; r < 4; r++) acc1[i][j][r] += b;
    }

    // LDS-transpose per output block: stage f32 [256][132], read coalesced
    float* ldsF = (float*)lds;   // 256*132*4 = 135168 B <= 144 KiB
    #pragma unroll
    for (int ob = 0; ob < 4; ob++) {
        if (ob) __syncthreads();   // previous block's reads done before reuse
        #pragma unroll
        for (int i = 0; i < 8; i++) {
            #pragma unroll
            for (int j = 0; j < 2; j++) {
                const int colL = wn * 32 + j * 16 + lr;
                #pragma unroll
                for (int r = 0; r < 4; r++) {
                    const int rowL = wm * 128 + i * 16 + kg * 4 + r;
                    const float i2 = acc1[i][j][r];
                    const float o1 = acc2[i][j][r];
                    const float val = (ob == 0) ? i2 : (ob == 1) ? o1
                                    : (ob == 2) ? i2 * o1 : otv[j] * o1;
                    ldsF[rowL * 132 + colL] = val;
                }
            }
        }
        __syncthreads();
        #pragma unroll
        for (int k = 0; k < 16; k++) {
            const int idx = t + k * 512;
            const int row = idx >> 5, seg = idx & 31;
            f32x4 v = *(const f32x4*)&ldsF[row * 132 + seg * 4];
            *(f32x4*)&out0[(size_t)(m0 + row) * 4096 + ob * 1024 + n0 + seg * 4] = v;
        }
    }
}

// ==== fused att GEMM + row softmax: 2 col-passes, 3-buffer counted vmcnt =
__global__ __launch_bounds__(512, 1) void att_softmax(
    const u16* __restrict__ A, const u16* __restrict__ B,
    const float* __restrict__ idot, const float* __restrict__ mdotm,
    u16* __restrict__ P, float* __restrict__ rowmax) {
    constexpr int ABUF = 64 * 64;          // u16
    constexpr int BBUF = 256 * 64;         // u16
    constexpr int BUFE = ABUF + BBUF;      // 20480 u16 = 40 KB
    __shared__ __align__(16) u16 lds[3 * BUFE];   // 120 KB
    const int t = threadIdx.x, lane = t & 63, wave = t >> 6;
    const int wm = wave >> 2, wn = wave & 3;
    const int lr = lane & 15, kg = lane >> 4;
    const int bid = blockIdx.x;                    // 256 blocks
    const int swz = (bid & 7) * 32 + (bid >> 3);   // XCD swizzle
    const int m0 = swz * 64;
    const int nb = m0 >> 11;                       // /LD
    const u16* Bp = B + (size_t)nb * LM * DD;

    const int srow = lane >> 3;
    const u16* gA;
    {
        const int colb = ((lane & 7) * 16) ^ ((((wave << 2) + (lane >> 4)) & 7) << 4);
        gA = A + (size_t)(m0 + wave * 8 + srow) * DD + (colb >> 1);
    }
    const u16* gB[4];
    #pragma unroll
    for (int i = 0; i < 4; i++) {
        const int c = wave * 4 + i;                // 0..31 (256 B-rows)
        const int colb = ((lane & 7) * 16) ^ ((((c << 2) + (lane >> 4)) & 7) << 4);
        gB[i] = Bp + (size_t)(c * 8 + srow) * DD + (colb >> 1);
    }
    int offA[2], offB[4];
    #pragma unroll
    for (int i = 0; i < 2; i++) {
        const int row = wm * 32 + i * 16 + lr;
        offA[i] = (row * 128 + kg * 16) ^ (((row >> 1) & 7) << 4);
    }
    #pragma unroll
    for (int j = 0; j < 4; j++) {
        const int row = wn * 64 + j * 16 + lr;
        offB[j] = (ABUF * 2 + row * 128 + kg * 16) ^ (((row >> 1) & 7) << 4);
    }

    f32x4 acc[2][8];
    #pragma unroll
    for (int i = 0; i < 2; i++)
        #pragma unroll
        for (int j = 0; j < 8; j++) acc[i][j] = (f32x4){0.f, 0.f, 0.f, 0.f};

    #define ASTAGE(tt, buf, pofs) do {                                      \
        u16* la_ = &lds[(buf) * BUFE];                                      \
        u16* lb_ = la_ + ABUF;                                              \
        const int ko_ = (tt) * 64;                                          \
        GLOAD_LDS16(gA + ko_, la_ + wave * 512);                            \
        _Pragma("unroll")                                                   \
        for (int i_ = 0; i_ < 4; i_++)                                      \
            GLOAD_LDS16(gB[i_] + (pofs) + ko_, lb_ + (wave * 4 + i_) * 512); \
    } while (0)

    for (int c = 0; c < 2; c++) {
        const size_t pofs = (size_t)c * 256 * DD;
        ASTAGE(0, 0, pofs);
        ASTAGE(1, 1, pofs);
        asm volatile("s_waitcnt vmcnt(5)" ::: "memory");
        __builtin_amdgcn_s_barrier();
        __builtin_amdgcn_sched_barrier(0);
        int cb = 0, sb = 2;
        for (int tt = 0; tt < 16; ++tt) {
            if (tt + 2 < 16) ASTAGE(tt + 2, sb, pofs);
            __builtin_amdgcn_sched_barrier(0);
            const char* bb = (const char*)&lds[cb * BUFE];
            short8 af[2][2];
            #pragma unroll
            for (int i = 0; i < 2; i++)
                #pragma unroll
                for (int kh = 0; kh < 2; kh++)
                    af[i][kh] = *(const short8*)(bb + (offA[i] ^ (kh * 64)));
            #pragma unroll
            for (int j = 0; j < 4; j++) {
                short8 bf[2];
                #pragma unroll
                for (int kh = 0; kh < 2; kh++)
                    bf[kh] = *(const short8*)(bb + (offB[j] ^ (kh * 64)));
                __builtin_amdgcn_s_setprio(1);
                #pragma unroll
                for (int i = 0; i < 2; i++)
                    #pragma unroll
                    for (int kh = 0; kh < 2; kh++)
                        acc[i][c * 4 + j] = __builtin_amdgcn_mfma_f32_16x16x32_bf16(
                            af[i][kh], bf[kh], acc[i][c * 4 + j], 0, 0, 0);
                __builtin_amdgcn_s_setprio(0);
            }
            if (tt + 2 < 16)      asm volatile("s_waitcnt vmcnt(5)" ::: "memory");
            else if (tt + 1 < 16) asm volatile("s_waitcnt vmcnt(0)" ::: "memory");
            __builtin_amdgcn_s_barrier();
            __builtin_amdgcn_sched_barrier(0);
            cb = (cb == 2) ? 0 : cb + 1;
            sb = (sb == 2) ? 0 : sb + 1;
        }
    }
    #undef ASTAGE

    // ---- epilogue: add dots, row softmax over 512 cols, write P ---------
    // col(cj) = (cj>>2)*256 + wn*64 + (cj&3)*16 + lr
    float* redm = (float*)lds;        // [64][4]
    float* reds = redm + 256;         // [64][4]
    float mdv[8];
    #pragma unroll
    for (int cj = 0; cj < 8; cj++)
        mdv[cj] = mdotm[nb * LM + (cj >> 2) * 256 + wn * 64 + (cj & 3) * 16 + lr];
    float idv[8];
    #pragma unroll
    for (int i = 0; i < 2; i++)
        #pragma unroll
        for (int r = 0; r < 4; r++)
            idv[i * 4 + r] = idot[m0 + wm * 32 + i * 16 + kg * 4 + r];
    float pm[8];
    #pragma unroll
    for (int i = 0; i < 2; i++)
        #pragma unroll
        for (int r = 0; r < 4; r++) {
            float mx = -3.0e38f;
            #pragma unroll
            for (int cj = 0; cj < 8; cj++) {
                const float v = acc[i][cj][r] * 0.03125f + idv[i * 4 + r] + mdv[cj];
                acc[i][cj][r] = v;
                mx = fmaxf(mx, v);
            }
            pm[i * 4 + r] = mx;
        }
    #pragma unroll
    for (int w = 1; w < 16; w <<= 1)
        #pragma unroll
        for (int q = 0; q < 8; q++) pm[q] = fmaxf(pm[q], __shfl_xor(pm[q], w));
    if (lr == 0) {
        #pragma unroll
        for (int i = 0; i < 2; i++)
            #pragma unroll
            for (int r = 0; r < 4; r++)
                redm[(wm * 32 + i * 16 + kg * 4 + r) * 4 + wn] = pm[i * 4 + r];
    }
    __syncthreads();
    float Mr[8], ps[8];
    #pragma unroll
    for (int i = 0; i < 2; i++)
        #pragma unroll
        for (int r = 0; r < 4; r++) {
            const int row = wm * 32 + i * 16 + kg * 4 + r;
            const float a = fmaxf(redm[row * 4 + 0], redm[row * 4 + 1]);
            const float b = fmaxf(redm[row * 4 + 2], redm[row * 4 + 3]);
            Mr[i * 4 + r] = fmaxf(a, b);
            float s = 0.f;
            #pragma unroll
            for (int cj = 0; cj < 8; cj++) {
                const float e = __expf(acc[i][cj][r] - Mr[i * 4 + r]);
                acc[i][cj][r] = e;
                s += e;
            }
            ps[i * 4 + r] = s;
        }
    #pragma unroll
    for (int w = 1; w < 16; w <<= 1)
        #pragma unroll
        for (int q = 0; q < 8; q++) ps[q] += __shfl_xor(ps[q], w);
    if (lr == 0) {
        #pragma unroll
        for (int i = 0; i < 2; i++)
            #pragma unroll
            for (int r = 0; r < 4; r++)
                reds[(wm * 32 + i * 16 + kg * 4 + r) * 4 + wn] = ps[i * 4 + r];
    }
    __syncthreads();
    #pragma unroll
    for (int i = 0; i < 2; i++)
        #pragma unroll
        for (int r = 0; r < 4; r++) {
            const int row = wm * 32 + i * 16 + kg * 4 + r;
            const float inv = 1.0f / (reds[row * 4 + 0] + reds[row * 4 + 1] +
                                      reds[row * 4 + 2] + reds[row * 4 + 3]);
            if (wn == 0 && lr == 0) rowmax[m0 + row] = Mr[i * 4 + r];
            #pragma unroll
            for (int cj = 0; cj < 8; cj++)
                P[(size_t)(m0 + row) * LM +
                  (cj >> 2) * 256 + wn * 64 + (cj & 3) * 16 + lr] =
                    f2bf(acc[i][cj][r] * inv);
        }
}

// ---- output_two via xbar = sum_l w2[l] * x_l (bf16 input, 256 blocks) ---
__global__ __launch_bounds__(256) void xbar_partial(
    const float* __restrict__ rowmax, const u16* __restrict__ X,
    float* __restrict__ part) {
    const int lz = blockIdx.x, n = blockIdx.y, t = threadIdx.x;   // lz 0..31
    const float* rm = rowmax + (size_t)n * LD;
    float v[8];
    float m = -3.0e38f;
    #pragma unroll
    for (int i = 0; i < 8; i++) { v[i] = rm[t + i * 256]; m = fmaxf(m, v[i]); }
    #pragma unroll
    for (int off = 32; off; off >>= 1) m = fmaxf(m, __shfl_down(m, off));
    __shared__ float sm[4], ss[4];
    __shared__ float wl[64];
    if ((t & 63) == 0) sm[t >> 6] = m;
    __syncthreads();
    const float M = fmaxf(fmaxf(sm[0], sm[1]), fmaxf(sm[2], sm[3]));
    float s = 0.f;
    #pragma unroll
    for (int i = 0; i < 8; i++) s += __expf(v[i] - M);
    #pragma unroll
    for (int off = 32; off; off >>= 1) s += __shfl_down(s, off);
    if ((t & 63) == 0) ss[t >> 6] = s;
    __syncthreads();
    const float invS = 1.0f / (ss[0] + ss[1] + ss[2] + ss[3]);
    if (t < 64) wl[t] = __expf(rm[lz * 64 + t] - M) * invS;
    __syncthreads();
    const u16* xp = X + ((size_t)n * LD + lz * 64) * DD + t * 4;
    f32x4 acc = {0.f, 0.f, 0.f, 0.f};
    #pragma unroll 4
    for (int l = 0; l < 64; l++) {
        u16x4 x = *(const u16x4*)(xp + (size_t)l * DD);
        const float w = wl[l];
        acc[0] += w * bf2f(x[0]); acc[1] += w * bf2f(x[1]);
        acc[2] += w * bf2f(x[2]); acc[3] += w * bf2f(x[3]);
    }
    *(f32x4*)&part[((size_t)n * 32 + lz) * HID + t * 4] = acc;
}

// ot[n][h] = xbar[n]·Wt[h,:] + b[h]; 64 blocks (8 h-chunks x 8 n)
__global__ __launch_bounds__(256) void ot_final2(
    const float* __restrict__ part, const u16* __restrict__ Wt,
    const float* __restrict__ bias, float* __restrict__ ot) {
    const int hc = blockIdx.x, n = blockIdx.y, t = threadIdx.x;
    __shared__ float xb[HID];
    f32x4 s = {0.f, 0.f, 0.f, 0.f};
    #pragma unroll
    for (int i = 0; i < 32; i++) {
        f32x4 p = *(const f32x4*)&part[((size_t)n * 32 + i) * HID + t * 4];
        s[0] += p[0]; s[1] += p[1]; s[2] += p[2]; s[3] += p[3];
    }
    *(f32x4*)&xb[t * 4] = s;
    __syncthreads();
    const int h = hc * 128 + (t >> 1);
    const int d0 = (t & 1) * 512;
    float a = 0.f;
    #pragma unroll 4
    for (int d = 0; d < 512; d += 8) {
        short8 w8 = *(const short8*)&Wt[(size_t)h * DD + d0 + d];
        #pragma unroll
        for (int j = 0; j < 8; j++) a += bf2f((u16)w8[j]) * xb[d0 + d + j];
    }
    a += __shfl_xor(a, 1);
    if ((t & 1) == 0) ot[(size_t)n * HID + h] = a + bias[h];
}

extern "C" void kernel_launch(void* const* d_in, const int* in_sizes, int n_in,
                              void* d_out, int out_size, void* d_ws, size_t ws_size,
                              hipStream_t stream) {
    const float* input  = (const float*)d_in[0];
    const float* memory = (const float*)d_in[1];
    const float* mask   = (const float*)d_in[2];
    const float* in1_w  = (const float*)d_in[3];
    const float* mem1_w = (const float*)d_in[4];
    const float* in2_w  = (const float*)d_in[5];
    const float* in2_b  = (const float*)d_in[6];
    const float* mem2_w = (const float*)d_in[7];
    const float* mem2_b = (const float*)d_in[8];

    float* out = (float*)d_out;
    float* outTail = out + (size_t)M1 * 4096;  // mem2 output [N,LM,HID]

    char* ws = (char*)d_ws;
    size_t off = 0;
    auto alloc = [&](size_t bytes) -> void* {
        void* p = ws + off;
        off = (off + bytes + 255) & ~(size_t)255;
        return p;
    };
    u16* input_bf16  = (u16*)alloc((size_t)M1 * DD * 2);      // 33.5 MB
    u16* memory_bf16 = (u16*)alloc((size_t)M2 * DD * 2);      // 8.4 MB
    u16* in2_wt      = (u16*)alloc((size_t)HID * DD * 2);     // 2.1 MB
    u16* mem2_wt     = (u16*)alloc((size_t)HID * DD * 2);     // 2.1 MB
    u16* mem2t       = (u16*)alloc((size_t)NSEQ * HID * LM * 2);  // 8.4 MB
    u16* P           = (u16*)alloc((size_t)M1 * LM * 2);      // 16.8 MB
    float* idot      = (float*)alloc((size_t)M1 * 4);
    float* mdotm     = (float*)alloc((size_t)M2 * 4);
    float* rowmax    = (float*)alloc((size_t)M1 * 4);
    float* ot        = (float*)alloc((size_t)NSEQ * HID * 4);
    float* part      = (float*)alloc((size_t)NSEQ * 32 * HID * 4);

    // 1) bf16 casts + row dots + weight transposes (merged)
    prep_all<<<M1 + M2 + 2048, 256, 0, stream>>>(
        input, memory, in1_w, mem1_w, mask, in2_w, mem2_w,
        input_bf16, memory_bf16, in2_wt, mem2_wt, idot, mdotm);
    // 2) mem2 = memory @ mem2_w + b -> outTail f32 AND mem2t bf16 (fused)
    gemm_mem2<16><<<dim3(8, M2 / 128), 512, 0, stream>>>(
        memory_bf16, mem2_wt, outTail, mem2_b, mem2t);
    // 3) fused att GEMM + softmax -> P (bf16), rowmax
    att_softmax<<<M1 / 64, 512, 0, stream>>>(
        input_bf16, memory_bf16, idot, mdotm, P, rowmax);
    // 4) output_two = (sum_l w2 x_l) @ W2 + b
    xbar_partial<<<dim3(32, NSEQ), 256, 0, stream>>>(rowmax, input_bf16, part);
    ot_final2<<<dim3(8, NSEQ), 256, 0, stream>>>(part, in2_wt, in2_b, ot);
    // 5) fused inp2 + PV -> out blocks 0..3 (LDS-transpose epilogue)
    fused_gemm<<<dim3(8, M1 / 256), 512, 0, stream>>>(
        input_bf16, in2_wt, P, mem2t, out, in2_b, ot);
}